// Round 3
// baseline (910.630 us; speedup 1.0000x reference)
//
#include <hip/hip_runtime.h>
#include <hip/hip_bf16.h>

typedef __hip_bfloat16 bf16;

#define NN 32
#define CC 96
#define TT 256
#define VV 25
#define SS 3
#define RR 12
#define OO 96
#define BCC 24
#define TV (TT*VV)     /* 6400 */
#define VV2 (VV*VV)    /* 625  */

__device__ __forceinline__ float b2f(bf16 v){ return __bfloat162float(v); }
__device__ __forceinline__ bf16  f2b(float v){ return __float2bfloat16(v); }

// ---------------------------------------------------------------- K1: xm = mean_T(x)
__global__ __launch_bounds__(256) void k_mean(const float* __restrict__ x, float* __restrict__ xm)
{
    int idx = blockIdx.x*256 + threadIdx.x;          // (n*C + c)*V + v
    if (idx >= NN*CC*VV) return;
    int v  = idx % VV;
    int nc = idx / VV;
    const float* p = x + (size_t)nc*TV + v;
    float s = 0.f;
    for (int t=0;t<TT;t++) s += p[t*VV];
    xm[idx] = s * (1.0f/TT);
}

// ---------------------------------------------------------------- K2: A_at[n,s,o,u,v]
__global__ __launch_bounds__(256) void k_aat(
    const float* __restrict__ xm,
    const float* __restrict__ c1_w, const float* __restrict__ c1_b,
    const float* __restrict__ c2_w, const float* __restrict__ c2_b,
    const float* __restrict__ c4_w, const float* __restrict__ c4_b,
    const float* __restrict__ A3,  const float* __restrict__ A6, const float* __restrict__ spd,
    const float* __restrict__ alpha, const float* __restrict__ beta, const float* __restrict__ gamma,
    float* __restrict__ Aat)
{
    __shared__ float s_xm[CC*VV];        // 2400
    __shared__ float s_x1[RR*VV], s_x2[RR*VV];
    __shared__ float s_R[RR*VV2];        // 7500
    __shared__ float s_c4[OO*RR];        // 1152
    __shared__ float s_A3[VV2], s_spd[VV2];
    int n = blockIdx.x / SS, s = blockIdx.x % SS;
    int tid = threadIdx.x;
    for (int i=tid;i<CC*VV;i+=256) s_xm[i] = xm[(size_t)n*CC*VV + i];
    for (int i=tid;i<OO*RR;i+=256) s_c4[i] = c4_w[s*OO*RR + i];
    for (int i=tid;i<VV2;i+=256){ s_A3[i]=A3[s*VV2+i]; s_spd[i]=spd[i]; }
    __syncthreads();
    // x1/x2: [REL,V]
    for (int i=tid;i<RR*VV;i+=256){
        int r=i/VV, u=i-r*VV;
        float a1=0.f, a2=0.f;
        for (int c=0;c<CC;c++){
            float xv = s_xm[c*VV+u];
            a1 += c1_w[(s*RR+r)*CC+c]*xv;
            a2 += c2_w[(s*RR+r)*CC+c]*xv;
        }
        s_x1[i]=a1+c1_b[s*RR+r];
        s_x2[i]=a2+c2_b[s*RR+r];
    }
    __syncthreads();
    // R = tanh(x1[u] - x2[v])
    for (int i=tid;i<RR*VV2;i+=256){
        int r=i/VV2, uv=i-r*VV2, u=uv/VV, v=uv-u*VV;
        s_R[i] = tanhf(s_x1[r*VV+u]-s_x2[r*VV+v]);
    }
    __syncthreads();
    float al=alpha[0], be=beta[0], ga=gamma[0];
    float* op = Aat + ((size_t)n*SS+s)*OO*VV2;
    for (int i=tid;i<OO*VV2;i+=256){
        int o=i/VV2, uv=i-o*VV2;
        float m=0.f;
        #pragma unroll
        for (int r=0;r<RR;r++) m += s_c4[o*RR+r]*s_R[r*VV2+uv];
        m += c4_b[s*OO+o];
        op[i] = m*al + s_A3[uv] + A6[(o%6)*VV2+uv]*be + s_spd[uv]*ga;
    }
}

// ---------------------------------------------------------------- K3: fused GCN -> y (stored in d_out)
// block = (n, og[4 o's], 32-t tile); stage1: x3 into LDS; stage2: A in regs.
__global__ __launch_bounds__(256,2) void k_gcn(
    const float* __restrict__ x, const float* __restrict__ c3_w, const float* __restrict__ c3_b,
    const float* __restrict__ Aat, const float* __restrict__ gbn_s, const float* __restrict__ gbn_b,
    float* __restrict__ y)
{
    __shared__ __align__(16) float s_w[CC*16];      // [c][k(12) pad16]
    __shared__ float s_cb[12];
    __shared__ __align__(16) float s_x3[12*896];    // [k][tc*28 + v], 32*28=896
    int bi = blockIdx.x;
    int og  = bi % 24;
    int tcb = (bi/24) & 7;
    int n   = bi / 192;
    int t0  = tcb*32;
    int tid = threadIdx.x;

    for (int i=tid;i<CC*12;i+=256){
        int c=i/12, k=i-c*12, s=k>>2, op=k&3;
        s_w[c*16+k] = c3_w[(s*OO + og*4+op)*CC + c];
    }
    if (tid<12){ int s=tid>>2, op=tid&3; s_cb[tid] = c3_b[s*OO + og*4+op]; }
    __syncthreads();

    // ---- stage 1: x3[k][p] for p = tc*25+v in [0,800)
    float acc[4][12];
    #pragma unroll
    for (int j=0;j<4;j++)
        #pragma unroll
        for (int k=0;k<12;k++) acc[j][k]=0.f;
    size_t xb = (size_t)n*CC*TV + (size_t)t0*VV;
    int p3 = (tid<32) ? (768+tid) : 799;
    for (int c=0;c<CC;c++){
        float wv[12];
        *(float4*)&wv[0] = *(const float4*)&s_w[c*16];
        *(float4*)&wv[4] = *(const float4*)&s_w[c*16+4];
        *(float4*)&wv[8] = *(const float4*)&s_w[c*16+8];
        const float* xc = x + xb + (size_t)c*TV;
        float xv[4];
        xv[0]=xc[tid]; xv[1]=xc[tid+256]; xv[2]=xc[tid+512]; xv[3]=xc[p3];
        #pragma unroll
        for (int j=0;j<4;j++)
            #pragma unroll
            for (int k=0;k<12;k++) acc[j][k] += wv[k]*xv[j];
    }
    #pragma unroll
    for (int j=0;j<4;j++){
        int p = (j<3) ? (tid + j*256) : p3;
        bool wr = (j<3) || (tid<32);
        if (wr){
            int tc=p/25, v=p-tc*25;
            #pragma unroll
            for (int k=0;k<12;k++) s_x3[k*896 + tc*28 + v] = acc[j][k] + s_cb[k];
        }
    }
    __syncthreads();

    // ---- stage 2: y[t,u] = sum_{s,v} A[s,u,v]*x3[s,t,v]
    int w  = tid >> 6;          // wave id = local o
    int L  = tid & 63;
    int u  = L & 31;
    int th = L >> 5;
    int o  = og*4 + w;
    int u_eff = (u<VV)?u:(VV-1);
    float areg[75];
    #pragma unroll
    for (int s=0;s<3;s++){
        const float* Ap = Aat + (((size_t)n*SS+s)*OO + o)*VV2 + (size_t)u_eff*VV;
        #pragma unroll
        for (int v=0;v<25;v++) areg[s*25+v] = Ap[v];
    }
    float gs = gbn_s[o], gb = gbn_b[o];
    for (int ti=0; ti<16; ti++){
        int tl = ti*2 + th;
        float a2 = 0.f;
        #pragma unroll
        for (int s=0;s<3;s++){
            const float* xr = &s_x3[(s*4+w)*896 + tl*28];
            #pragma unroll
            for (int vc=0; vc<6; vc++){
                float4 xv4 = *(const float4*)(xr + vc*4);
                a2 += xv4.x*areg[s*25+vc*4]   + xv4.y*areg[s*25+vc*4+1]
                    + xv4.z*areg[s*25+vc*4+2] + xv4.w*areg[s*25+vc*4+3];
            }
            a2 += xr[24]*areg[s*25+24];
        }
        if (u < VV){
            int t = t0 + tl;
            size_t oix = ((size_t)(n*OO+o)*TT + t)*VV + u;
            float yv = gs*a2 + gb + x[oix];
            y[oix] = yv>0.f?yv:0.f;
        }
    }
}

// ---------------------------------------------------------------- K4a: pointwise, branches 0..2 -> h1 (bf16)
__global__ __launch_bounds__(256,2) void k_pw_h(
    const float* __restrict__ yws, const float* __restrict__ pw_w, const float* __restrict__ pw_b,
    const float* __restrict__ pwbn_s, const float* __restrict__ pwbn_b,
    bf16* __restrict__ h1)
{
    __shared__ __align__(16) float s_w[OO*BCC];   // [o][cp]
    __shared__ float s_sc[BCC], s_sh[BCC];
    int b   = blockIdx.x/160;                     // 0..2
    int rem = blockIdx.x - b*160;
    int n   = rem/5;
    int chunk = rem - (rem/5)*5;
    int pbase = chunk*256 + threadIdx.x;          // p_j = pbase + j*1280, j<5
    for (int i=threadIdx.x;i<OO*BCC;i+=256){
        int o=i/BCC, cp=i-o*BCC;
        s_w[i] = pw_w[(b*BCC+cp)*OO + o];
    }
    if (threadIdx.x<BCC){
        int cp=threadIdx.x;
        float sc = pwbn_s[b*BCC+cp];
        s_sc[cp]=sc;
        s_sh[cp]= sc*pw_b[b*BCC+cp] + pwbn_b[b*BCC+cp];
    }
    __syncthreads();
    float acc[5][BCC];
    #pragma unroll
    for (int j=0;j<5;j++)
        #pragma unroll
        for (int i=0;i<BCC;i++) acc[j][i]=0.f;
    const float* yp = yws + (size_t)n*OO*TV + pbase;
    for (int o=0;o<OO;o++){
        float wv[BCC];
        #pragma unroll
        for (int q=0;q<6;q++) *(float4*)&wv[q*4] = *(const float4*)&s_w[o*BCC + q*4];
        float yv[5];
        #pragma unroll
        for (int j=0;j<5;j++) yv[j] = yp[(size_t)o*TV + j*1280];
        #pragma unroll
        for (int j=0;j<5;j++)
            #pragma unroll
            for (int cp=0;cp<BCC;cp++) acc[j][cp] += wv[cp]*yv[j];
    }
    size_t hb = ((size_t)(b*NN+n)*BCC)*TV + pbase;
    #pragma unroll
    for (int j=0;j<5;j++)
        #pragma unroll
        for (int cp=0;cp<BCC;cp++){
            float h = s_sc[cp]*acc[j][cp] + s_sh[cp];
            h1[hb + (size_t)cp*TV + j*1280] = f2b(h>0.f?h:0.f);
        }
}

// ---------------------------------------------------------------- K4b: pointwise branch 3 -> out ch 72..95
// In-place on yout: per-thread all reads precede all writes; point sets disjoint across threads/blocks.
__global__ __launch_bounds__(256,2) void k_pw3(
    float* yout, const float* __restrict__ pw_w, const float* __restrict__ pw_b,
    const float* __restrict__ pwbn_s, const float* __restrict__ pwbn_b,
    const float* __restrict__ x)
{
    __shared__ __align__(16) float s_w[OO*BCC];
    __shared__ float s_sc[BCC], s_sh[BCC];
    const int b = 3;
    int n   = blockIdx.x/5;
    int chunk = blockIdx.x - n*5;
    int pbase = chunk*256 + threadIdx.x;
    for (int i=threadIdx.x;i<OO*BCC;i+=256){
        int o=i/BCC, cp=i-o*BCC;
        s_w[i] = pw_w[(b*BCC+cp)*OO + o];
    }
    if (threadIdx.x<BCC){
        int cp=threadIdx.x;
        float sc = pwbn_s[b*BCC+cp];
        s_sc[cp]=sc;
        s_sh[cp]= sc*pw_b[b*BCC+cp] + pwbn_b[b*BCC+cp];
    }
    __syncthreads();
    float acc[5][BCC];
    #pragma unroll
    for (int j=0;j<5;j++)
        #pragma unroll
        for (int i=0;i<BCC;i++) acc[j][i]=0.f;
    const float* yp = yout + (size_t)n*OO*TV + pbase;
    for (int o=0;o<OO;o++){
        float wv[BCC];
        #pragma unroll
        for (int q=0;q<6;q++) *(float4*)&wv[q*4] = *(const float4*)&s_w[o*BCC + q*4];
        float yv[5];
        #pragma unroll
        for (int j=0;j<5;j++) yv[j] = yp[(size_t)o*TV + j*1280];
        #pragma unroll
        for (int j=0;j<5;j++)
            #pragma unroll
            for (int cp=0;cp<BCC;cp++) acc[j][cp] += wv[cp]*yv[j];
    }
    size_t ob = ((size_t)n*OO + 72)*TV + pbase;
    #pragma unroll
    for (int j=0;j<5;j++)
        #pragma unroll
        for (int cp=0;cp<BCC;cp++){
            float h = s_sc[cp]*acc[j][cp] + s_sh[cp];
            size_t ix = ob + (size_t)cp*TV + j*1280;
            float r = h + x[ix];
            yout[ix] = r>0.f?r:0.f;
        }
}

// ---------------------------------------------------------------- K5: temporal convs + maxpool -> out ch 0..71
template<int B>
__device__ __forceinline__ void conv_body(
    int n, int cp, int t0, int v,
    const bf16* __restrict__ h1, const float* __restrict__ tc_w, const float* __restrict__ tc_b,
    const float* __restrict__ tcbn_s, const float* __restrict__ tcbn_b,
    const float* __restrict__ x, float* __restrict__ out)
{
    const int D = B+1;                // DILS = (1,2)
    const int W = 4 + 4*D;            // window length for 4 outputs
    float acc[4] = {0.f,0.f,0.f,0.f};
    const bf16* hbase = h1 + ((size_t)(B*NN+n)*BCC)*TV + v;
    for (int ci=0; ci<BCC; ci++){
        const bf16* hc = hbase + (size_t)ci*TV;
        float win[W];
        #pragma unroll
        for (int j=0;j<W;j++){
            int tt = t0 - 2*D + j;
            win[j] = (tt>=0 && tt<TT) ? b2f(hc[tt*VV]) : 0.f;
        }
        const float* wp = tc_w + ((B*BCC+cp)*BCC + ci)*5;
        float w0=wp[0],w1=wp[1],w2=wp[2],w3=wp[3],w4=wp[4];
        #pragma unroll
        for (int i=0;i<4;i++)
            acc[i] += w0*win[i] + w1*win[i+D] + w2*win[i+2*D] + w3*win[i+3*D] + w4*win[i+4*D];
    }
    int ch = B*BCC+cp;
    float tbias=tc_b[ch], ts=tcbn_s[ch], tb=tcbn_b[ch];
    #pragma unroll
    for (int i=0;i<4;i++){
        size_t oix = ((size_t)(n*OO+ch)*TT + (t0+i))*VV + v;
        float r = ts*(acc[i]+tbias) + tb + x[oix];
        out[oix] = r>0.f?r:0.f;
    }
}

__global__ __launch_bounds__(256,4) void k_tcn(
    const bf16* __restrict__ h1, const float* __restrict__ tc_w, const float* __restrict__ tc_b,
    const float* __restrict__ tcbn_s, const float* __restrict__ tcbn_b,
    const float* __restrict__ mpbn_s, const float* __restrict__ mpbn_b,
    const float* __restrict__ x, float* __restrict__ out)
{
    int g  = blockIdx.x*256 + threadIdx.x;   // (n, bc[72], t4[64], v[25])
    int v  = g % 25;
    int t4 = (g/25) & 63;
    int bc = (g/1600) % 72;
    int n  = g / 115200;
    int b  = bc/24, cp = bc - b*24;
    int t0 = t4*4;
    if (b==0){
        conv_body<0>(n,cp,t0,v,h1,tc_w,tc_b,tcbn_s,tcbn_b,x,out);
    } else if (b==1){
        conv_body<1>(n,cp,t0,v,h1,tc_w,tc_b,tcbn_s,tcbn_b,x,out);
    } else {
        const bf16* hc = h1 + ((size_t)(2*NN+n)*BCC + cp)*TV + v;
        float win[6];
        #pragma unroll
        for (int j=0;j<6;j++){
            int tt = t0-1+j;
            win[j] = (tt>=0 && tt<TT) ? b2f(hc[tt*VV]) : -3.0e38f;
        }
        float ms=mpbn_s[cp], mb=mpbn_b[cp];
        #pragma unroll
        for (int i=0;i<4;i++){
            float m = fmaxf(fmaxf(win[i],win[i+1]),win[i+2]);
            size_t oix = ((size_t)(n*OO+(48+cp))*TT + (t0+i))*VV + v;
            float r = ms*m + mb + x[oix];
            out[oix] = r>0.f?r:0.f;
        }
    }
}

// ----------------------------------------------------------------
// Workspace budget (29,491,200 B total):
//   phase A: xm fp32 [0, 307200) ; Aat fp32 [307200, 23,347,200)   (dead after k_gcn)
//   phase B: h1 bf16 [0, 29,491,200)                               (aliases phase A)
//   y lives in d_out (fp32), overwritten in-place by k_pw3/k_tcn afterwards.
extern "C" void kernel_launch(void* const* d_in, const int* in_sizes, int n_in,
                              void* d_out, int out_size, void* d_ws, size_t ws_size,
                              hipStream_t stream)
{
    const float* x     = (const float*)d_in[0];
    const float* spd   = (const float*)d_in[1];
    const float* A3    = (const float*)d_in[2];
    const float* A6    = (const float*)d_in[3];
    const float* alpha = (const float*)d_in[4];
    const float* beta  = (const float*)d_in[5];
    const float* gamma = (const float*)d_in[6];
    const float* c1_w  = (const float*)d_in[7];
    const float* c1_b  = (const float*)d_in[8];
    const float* c2_w  = (const float*)d_in[9];
    const float* c2_b  = (const float*)d_in[10];
    const float* c4_w  = (const float*)d_in[11];
    const float* c4_b  = (const float*)d_in[12];
    const float* c3_w  = (const float*)d_in[13];
    const float* c3_b  = (const float*)d_in[14];
    const float* gbn_s = (const float*)d_in[15];
    const float* gbn_b = (const float*)d_in[16];
    const float* pw_w  = (const float*)d_in[17];
    const float* pw_b  = (const float*)d_in[18];
    const float* pwbn_s= (const float*)d_in[19];
    const float* pwbn_b= (const float*)d_in[20];
    const float* tc_w  = (const float*)d_in[21];
    const float* tc_b  = (const float*)d_in[22];
    const float* tcbn_s= (const float*)d_in[23];
    const float* tcbn_b= (const float*)d_in[24];
    const float* mpbn_s= (const float*)d_in[25];
    const float* mpbn_b= (const float*)d_in[26];
    float* out = (float*)d_out;

    char* ws = (char*)d_ws;
    float* xm  = (float*)(ws);
    float* Aat = (float*)(ws + 307200);
    bf16*  h1  = (bf16*)(ws);            // aliases xm/Aat (dead by then)

    k_mean<<<dim3(300), dim3(256), 0, stream>>>(x, xm);
    k_aat <<<dim3(96),  dim3(256), 0, stream>>>(xm, c1_w,c1_b,c2_w,c2_b,c4_w,c4_b,
                                                A3, A6, spd, alpha, beta, gamma, Aat);
    k_gcn <<<dim3(6144),dim3(256), 0, stream>>>(x, c3_w, c3_b, Aat, gbn_s, gbn_b, out);
    k_pw_h<<<dim3(480), dim3(256), 0, stream>>>(out, pw_w, pw_b, pwbn_s, pwbn_b, h1);
    k_pw3 <<<dim3(160), dim3(256), 0, stream>>>(out, pw_w, pw_b, pwbn_s, pwbn_b, x);
    k_tcn <<<dim3(14400),dim3(256),0, stream>>>(h1, tc_w, tc_b, tcbn_s, tcbn_b,
                                                mpbn_s, mpbn_b, x, out);
}

// Round 7
// 739.078 us; speedup vs baseline: 1.2321x; 1.2321x over previous
//
#include <hip/hip_runtime.h>
#include <hip/hip_bf16.h>

typedef __hip_bfloat16 bf16;

#define NN 32
#define CC 96
#define TT 256
#define VV 25
#define SS 3
#define RR 12
#define OO 96
#define BCC 24
#define TV (TT*VV)     /* 6400 */
#define VV2 (VV*VV)    /* 625  */

__device__ __forceinline__ float b2f(bf16 v){ return __bfloat162float(v); }
__device__ __forceinline__ bf16  f2b(float v){ return __float2bfloat16(v); }
// bf16 bits -> fp32
__device__ __forceinline__ float u2f(unsigned short b){
    union{unsigned u; float f;} a; a.u = ((unsigned)b)<<16; return a.f;
}

// ---------------------------------------------------------------- K1: xm = mean_T(x)
__global__ __launch_bounds__(256) void k_mean(const float* __restrict__ x, float* __restrict__ xm)
{
    int idx = blockIdx.x*256 + threadIdx.x;          // (n*C + c)*V + v
    if (idx >= NN*CC*VV) return;
    int v  = idx % VV;
    int nc = idx / VV;
    const float* p = x + (size_t)nc*TV + v;
    float s = 0.f;
    for (int t=0;t<TT;t++) s += p[t*VV];
    xm[idx] = s * (1.0f/TT);
}

// ---------------------------------------------------------------- K2: A_at[n,s,o,u,v]
__global__ __launch_bounds__(256) void k_aat(
    const float* __restrict__ xm,
    const float* __restrict__ c1_w, const float* __restrict__ c1_b,
    const float* __restrict__ c2_w, const float* __restrict__ c2_b,
    const float* __restrict__ c4_w, const float* __restrict__ c4_b,
    const float* __restrict__ A3,  const float* __restrict__ A6, const float* __restrict__ spd,
    const float* __restrict__ alpha, const float* __restrict__ beta, const float* __restrict__ gamma,
    float* __restrict__ Aat)
{
    __shared__ float s_xm[CC*VV];
    __shared__ float s_x1[RR*VV], s_x2[RR*VV];
    __shared__ float s_R[RR*VV2];
    __shared__ float s_c4[OO*RR];
    __shared__ float s_A3[VV2], s_spd[VV2];
    int n = blockIdx.x / SS, s = blockIdx.x % SS;
    int tid = threadIdx.x;
    for (int i=tid;i<CC*VV;i+=256) s_xm[i] = xm[(size_t)n*CC*VV + i];
    for (int i=tid;i<OO*RR;i+=256) s_c4[i] = c4_w[s*OO*RR + i];
    for (int i=tid;i<VV2;i+=256){ s_A3[i]=A3[s*VV2+i]; s_spd[i]=spd[i]; }
    __syncthreads();
    for (int i=tid;i<RR*VV;i+=256){
        int r=i/VV, u=i-r*VV;
        float a1=0.f, a2=0.f;
        for (int c=0;c<CC;c++){
            float xv = s_xm[c*VV+u];
            a1 += c1_w[(s*RR+r)*CC+c]*xv;
            a2 += c2_w[(s*RR+r)*CC+c]*xv;
        }
        s_x1[i]=a1+c1_b[s*RR+r];
        s_x2[i]=a2+c2_b[s*RR+r];
    }
    __syncthreads();
    for (int i=tid;i<RR*VV2;i+=256){
        int r=i/VV2, uv=i-r*VV2, u=uv/VV, v=uv-u*VV;
        s_R[i] = tanhf(s_x1[r*VV+u]-s_x2[r*VV+v]);
    }
    __syncthreads();
    float al=alpha[0], be=beta[0], ga=gamma[0];
    float* op = Aat + ((size_t)n*SS+s)*OO*VV2;
    for (int i=tid;i<OO*VV2;i+=256){
        int o=i/VV2, uv=i-o*VV2;
        float m=0.f;
        #pragma unroll
        for (int r=0;r<RR;r++) m += s_c4[o*RR+r]*s_R[r*VV2+uv];
        m += c4_b[s*OO+o];
        op[i] = m*al + s_A3[uv] + A6[(o%6)*VV2+uv]*be + s_spd[uv]*ga;
    }
}

// ---------------------------------------------------------------- K3: fused GCN -> y (in d_out)
// ROUND-3 KNOWN-GOOD VALU VERSION (MFMA variant has an unresolved defect; see journal).
__global__ __launch_bounds__(256,2) void k_gcn(
    const float* __restrict__ x, const float* __restrict__ c3_w, const float* __restrict__ c3_b,
    const float* __restrict__ Aat, const float* __restrict__ gbn_s, const float* __restrict__ gbn_b,
    float* __restrict__ y)
{
    __shared__ __align__(16) float s_w[CC*16];      // [c][k(12) pad16]
    __shared__ float s_cb[12];
    __shared__ __align__(16) float s_x3[12*896];    // [k][tc*28 + v], 32*28=896
    int bi = blockIdx.x;
    int og  = bi % 24;
    int tcb = (bi/24) & 7;
    int n   = bi / 192;
    int t0  = tcb*32;
    int tid = threadIdx.x;

    for (int i=tid;i<CC*12;i+=256){
        int c=i/12, k=i-c*12, s=k>>2, op=k&3;
        s_w[c*16+k] = c3_w[(s*OO + og*4+op)*CC + c];
    }
    if (tid<12){ int s=tid>>2, op=tid&3; s_cb[tid] = c3_b[s*OO + og*4+op]; }
    __syncthreads();

    // ---- stage 1: x3[k][p] for p = tc*25+v in [0,800)
    float acc[4][12];
    #pragma unroll
    for (int j=0;j<4;j++)
        #pragma unroll
        for (int k=0;k<12;k++) acc[j][k]=0.f;
    size_t xb = (size_t)n*CC*TV + (size_t)t0*VV;
    int p3 = (tid<32) ? (768+tid) : 799;
    for (int c=0;c<CC;c++){
        float wv[12];
        *(float4*)&wv[0] = *(const float4*)&s_w[c*16];
        *(float4*)&wv[4] = *(const float4*)&s_w[c*16+4];
        *(float4*)&wv[8] = *(const float4*)&s_w[c*16+8];
        const float* xc = x + xb + (size_t)c*TV;
        float xv[4];
        xv[0]=xc[tid]; xv[1]=xc[tid+256]; xv[2]=xc[tid+512]; xv[3]=xc[p3];
        #pragma unroll
        for (int j=0;j<4;j++)
            #pragma unroll
            for (int k=0;k<12;k++) acc[j][k] += wv[k]*xv[j];
    }
    #pragma unroll
    for (int j=0;j<4;j++){
        int p = (j<3) ? (tid + j*256) : p3;
        bool wr = (j<3) || (tid<32);
        if (wr){
            int tc=p/25, v=p-tc*25;
            #pragma unroll
            for (int k=0;k<12;k++) s_x3[k*896 + tc*28 + v] = acc[j][k] + s_cb[k];
        }
    }
    __syncthreads();

    // ---- stage 2: y[t,u] = sum_{s,v} A[s,u,v]*x3[s,t,v]
    int w  = tid >> 6;          // wave id = local o
    int L  = tid & 63;
    int u  = L & 31;
    int th = L >> 5;
    int o  = og*4 + w;
    int u_eff = (u<VV)?u:(VV-1);
    float areg[75];
    #pragma unroll
    for (int s=0;s<3;s++){
        const float* Ap = Aat + (((size_t)n*SS+s)*OO + o)*VV2 + (size_t)u_eff*VV;
        #pragma unroll
        for (int v=0;v<25;v++) areg[s*25+v] = Ap[v];
    }
    float gs = gbn_s[o], gb = gbn_b[o];
    for (int ti=0; ti<16; ti++){
        int tl = ti*2 + th;
        float a2 = 0.f;
        #pragma unroll
        for (int s=0;s<3;s++){
            const float* xr = &s_x3[(s*4+w)*896 + tl*28];
            #pragma unroll
            for (int vc=0; vc<6; vc++){
                float4 xv4 = *(const float4*)(xr + vc*4);
                a2 += xv4.x*areg[s*25+vc*4]   + xv4.y*areg[s*25+vc*4+1]
                    + xv4.z*areg[s*25+vc*4+2] + xv4.w*areg[s*25+vc*4+3];
            }
            a2 += xr[24]*areg[s*25+24];
        }
        if (u < VV){
            int t = t0 + tl;
            size_t oix = ((size_t)(n*OO+o)*TT + t)*VV + u;
            float yv = gs*a2 + gb + x[oix];
            y[oix] = yv>0.f?yv:0.f;
        }
    }
}

// ---------------------------------------------------------------- K4a: pointwise, branches 0..2 -> h1 (bf16)
__global__ __launch_bounds__(256,2) void k_pw_h(
    const float* __restrict__ yws, const float* __restrict__ pw_w, const float* __restrict__ pw_b,
    const float* __restrict__ pwbn_s, const float* __restrict__ pwbn_b,
    bf16* __restrict__ h1)
{
    __shared__ __align__(16) float s_w[OO*BCC];
    __shared__ float s_sc[BCC], s_sh[BCC];
    int b   = blockIdx.x/160;
    int rem = blockIdx.x - b*160;
    int n   = rem/5;
    int chunk = rem - (rem/5)*5;
    int pbase = chunk*256 + threadIdx.x;
    for (int i=threadIdx.x;i<OO*BCC;i+=256){
        int o=i/BCC, cp=i-o*BCC;
        s_w[i] = pw_w[(b*BCC+cp)*OO + o];
    }
    if (threadIdx.x<BCC){
        int cp=threadIdx.x;
        float sc = pwbn_s[b*BCC+cp];
        s_sc[cp]=sc;
        s_sh[cp]= sc*pw_b[b*BCC+cp] + pwbn_b[b*BCC+cp];
    }
    __syncthreads();
    float acc[5][BCC];
    #pragma unroll
    for (int j=0;j<5;j++)
        #pragma unroll
        for (int i=0;i<BCC;i++) acc[j][i]=0.f;
    const float* yp = yws + (size_t)n*OO*TV + pbase;
    for (int o=0;o<OO;o++){
        float wv[BCC];
        #pragma unroll
        for (int q=0;q<6;q++) *(float4*)&wv[q*4] = *(const float4*)&s_w[o*BCC + q*4];
        float yv[5];
        #pragma unroll
        for (int j=0;j<5;j++) yv[j] = yp[(size_t)o*TV + j*1280];
        #pragma unroll
        for (int j=0;j<5;j++)
            #pragma unroll
            for (int cp=0;cp<BCC;cp++) acc[j][cp] += wv[cp]*yv[j];
    }
    size_t hb = ((size_t)(b*NN+n)*BCC)*TV + pbase;
    #pragma unroll
    for (int j=0;j<5;j++)
        #pragma unroll
        for (int cp=0;cp<BCC;cp++){
            float h = s_sc[cp]*acc[j][cp] + s_sh[cp];
            h1[hb + (size_t)cp*TV + j*1280] = f2b(h>0.f?h:0.f);
        }
}

// ---------------------------------------------------------------- K4b: pointwise branch 3 -> out ch 72..95
__global__ __launch_bounds__(256,2) void k_pw3(
    float* yout, const float* __restrict__ pw_w, const float* __restrict__ pw_b,
    const float* __restrict__ pwbn_s, const float* __restrict__ pwbn_b,
    const float* __restrict__ x)
{
    __shared__ __align__(16) float s_w[OO*BCC];
    __shared__ float s_sc[BCC], s_sh[BCC];
    const int b = 3;
    int n   = blockIdx.x/5;
    int chunk = blockIdx.x - n*5;
    int pbase = chunk*256 + threadIdx.x;
    for (int i=threadIdx.x;i<OO*BCC;i+=256){
        int o=i/BCC, cp=i-o*BCC;
        s_w[i] = pw_w[(b*BCC+cp)*OO + o];
    }
    if (threadIdx.x<BCC){
        int cp=threadIdx.x;
        float sc = pwbn_s[b*BCC+cp];
        s_sc[cp]=sc;
        s_sh[cp]= sc*pw_b[b*BCC+cp] + pwbn_b[b*BCC+cp];
    }
    __syncthreads();
    float acc[5][BCC];
    #pragma unroll
    for (int j=0;j<5;j++)
        #pragma unroll
        for (int i=0;i<BCC;i++) acc[j][i]=0.f;
    const float* yp = yout + (size_t)n*OO*TV + pbase;
    for (int o=0;o<OO;o++){
        float wv[BCC];
        #pragma unroll
        for (int q=0;q<6;q++) *(float4*)&wv[q*4] = *(const float4*)&s_w[o*BCC + q*4];
        float yv[5];
        #pragma unroll
        for (int j=0;j<5;j++) yv[j] = yp[(size_t)o*TV + j*1280];
        #pragma unroll
        for (int j=0;j<5;j++)
            #pragma unroll
            for (int cp=0;cp<BCC;cp++) acc[j][cp] += wv[cp]*yv[j];
    }
    size_t ob = ((size_t)n*OO + 72)*TV + pbase;
    #pragma unroll
    for (int j=0;j<5;j++)
        #pragma unroll
        for (int cp=0;cp<BCC;cp++){
            float h = s_sc[cp]*acc[j][cp] + s_sh[cp];
            size_t ix = ob + (size_t)cp*TV + j*1280;
            float r = h + x[ix];
            yout[ix] = r>0.f?r:0.f;
        }
}

// ---------------------------------------------------------------- K5: temporal convs + maxpool -> out ch 0..71
// NEW LDS-tiled version (tested in isolation this round).
template<int D>
__device__ __forceinline__ void tcn_conv(int n, int br, int t0, int t4, int v, int vv, bool act,
    const float* __restrict__ tc_w, const float* __restrict__ tc_b,
    const float* __restrict__ tcbn_s, const float* __restrict__ tcbn_b,
    const float* __restrict__ x, float* __restrict__ out, const unsigned short* s_h)
{
    const int W = 4 + 4*D;
    int tb = 4 + t4*4 - 2*D;
    for (int g=0; g<4; g++){
        float acc[6][4];
        #pragma unroll
        for (int cpi=0;cpi<6;cpi++)
            #pragma unroll
            for (int i=0;i<4;i++) acc[cpi][i]=0.f;
        for (int ci=0; ci<24; ci++){
            float win[W];
            #pragma unroll
            for (int j=0;j<W;j++) win[j] = u2f(s_h[(ci*40 + tb + j)*26 + vv]);
            #pragma unroll
            for (int cpi=0; cpi<6; cpi++){
                int cp = g*6+cpi;
                const float* wp = tc_w + ((br*BCC+cp)*BCC + ci)*5;   // uniform -> s_load
                float w0=wp[0],w1=wp[1],w2=wp[2],w3=wp[3],w4=wp[4];
                #pragma unroll
                for (int i=0;i<4;i++)
                    acc[cpi][i] += w0*win[i] + w1*win[i+D] + w2*win[i+2*D]
                                 + w3*win[i+3*D] + w4*win[i+4*D];
            }
        }
        if (act){
            #pragma unroll
            for (int cpi=0; cpi<6; cpi++){
                int ch = br*BCC + g*6+cpi;
                float tbias=tc_b[ch], ts=tcbn_s[ch], tb2=tcbn_b[ch];
                #pragma unroll
                for (int i=0;i<4;i++){
                    size_t oix = ((size_t)(n*OO+ch)*TT + (t0+t4*4+i))*VV + v;
                    float r = ts*(acc[cpi][i]+tbias) + tb2 + x[oix];
                    out[oix] = r>0.f?r:0.f;
                }
            }
        }
    }
}

__global__ __launch_bounds__(256,2) void k_tcn(
    const bf16* __restrict__ h1, const float* __restrict__ tc_w, const float* __restrict__ tc_b,
    const float* __restrict__ tcbn_s, const float* __restrict__ tcbn_b,
    const float* __restrict__ mpbn_s, const float* __restrict__ mpbn_b,
    const float* __restrict__ x, float* __restrict__ out)
{
    __shared__ unsigned short s_h[24*40*26];   // 49,920 B
    int bi  = blockIdx.x;
    int n   = bi / 24;
    int rem = bi % 24;
    int br  = rem >> 3;        // 0,1 = conv branches; 2 = maxpool
    int tcb = rem & 7;
    int t0  = tcb*32;
    int tid = threadIdx.x;

    const unsigned short* hb = (const unsigned short*)(h1 + ((size_t)(br*NN+n)*BCC)*TV);
    unsigned short padv = (br==2) ? (unsigned short)0xFF80 : (unsigned short)0;  // -inf / 0
    for (int ci=0; ci<24; ci++){
        const unsigned short* hc = hb + (size_t)ci*TV;
        #pragma unroll
        for (int j=0;j<5;j++){
            int idx = j*256 + tid;
            if (idx < 1040){
                int tt = idx/26, v = idx - tt*26;
                int gt = t0 - 4 + tt;
                unsigned short bits = padv;
                if (v<25 && gt>=0 && gt<TT) bits = hc[gt*VV+v];
                s_h[(ci*40+tt)*26 + v] = bits;
            }
        }
    }
    __syncthreads();

    int t4 = tid>>5, v = tid&31;
    bool act = v<25;
    int vv = act ? v : 24;

    if (br==0){
        tcn_conv<1>(n,br,t0,t4,v,vv,act,tc_w,tc_b,tcbn_s,tcbn_b,x,out,s_h);
    } else if (br==1){
        tcn_conv<2>(n,br,t0,t4,v,vv,act,tc_w,tc_b,tcbn_s,tcbn_b,x,out,s_h);
    } else {
        int tb = 4 + t4*4 - 1;
        for (int cp=0; cp<24; cp++){
            float win[6];
            #pragma unroll
            for (int j=0;j<6;j++) win[j] = u2f(s_h[(cp*40 + tb + j)*26 + vv]);
            float ms=mpbn_s[cp], mb=mpbn_b[cp];
            if (act){
                #pragma unroll
                for (int i=0;i<4;i++){
                    float m = fmaxf(fmaxf(win[i],win[i+1]),win[i+2]);
                    size_t oix = ((size_t)(n*OO+(48+cp))*TT + (t0+t4*4+i))*VV + v;
                    float r = ms*m + mb + x[oix];
                    out[oix] = r>0.f?r:0.f;
                }
            }
        }
    }
}

// ----------------------------------------------------------------
// Workspace (29,491,200 B): phase A: xm [0,307200) + Aat [307200, 23,347,200)
//                           phase B: h1 bf16 [0, 29,491,200) (aliases A; A dead after k_gcn)
// y lives in d_out (fp32), overwritten in place by k_pw3/k_tcn.
extern "C" void kernel_launch(void* const* d_in, const int* in_sizes, int n_in,
                              void* d_out, int out_size, void* d_ws, size_t ws_size,
                              hipStream_t stream)
{
    const float* x     = (const float*)d_in[0];
    const float* spd   = (const float*)d_in[1];
    const float* A3    = (const float*)d_in[2];
    const float* A6    = (const float*)d_in[3];
    const float* alpha = (const float*)d_in[4];
    const float* beta  = (const float*)d_in[5];
    const float* gamma = (const float*)d_in[6];
    const float* c1_w  = (const float*)d_in[7];
    const float* c1_b  = (const float*)d_in[8];
    const float* c2_w  = (const float*)d_in[9];
    const float* c2_b  = (const float*)d_in[10];
    const float* c4_w  = (const float*)d_in[11];
    const float* c4_b  = (const float*)d_in[12];
    const float* c3_w  = (const float*)d_in[13];
    const float* c3_b  = (const float*)d_in[14];
    const float* gbn_s = (const float*)d_in[15];
    const float* gbn_b = (const float*)d_in[16];
    const float* pw_w  = (const float*)d_in[17];
    const float* pw_b  = (const float*)d_in[18];
    const float* pwbn_s= (const float*)d_in[19];
    const float* pwbn_b= (const float*)d_in[20];
    const float* tc_w  = (const float*)d_in[21];
    const float* tc_b  = (const float*)d_in[22];
    const float* tcbn_s= (const float*)d_in[23];
    const float* tcbn_b= (const float*)d_in[24];
    const float* mpbn_s= (const float*)d_in[25];
    const float* mpbn_b= (const float*)d_in[26];
    float* out = (float*)d_out;

    char* ws = (char*)d_ws;
    float* xm  = (float*)(ws);
    float* Aat = (float*)(ws + 307200);
    bf16*  h1  = (bf16*)(ws);            // aliases xm/Aat (dead by then)

    k_mean<<<dim3(300), dim3(256), 0, stream>>>(x, xm);
    k_aat <<<dim3(96),  dim3(256), 0, stream>>>(xm, c1_w,c1_b,c2_w,c2_b,c4_w,c4_b,
                                                A3, A6, spd, alpha, beta, gamma, Aat);
    k_gcn <<<dim3(6144),dim3(256), 0, stream>>>(x, c3_w, c3_b, Aat, gbn_s, gbn_b, out);
    k_pw_h<<<dim3(480), dim3(256), 0, stream>>>(out, pw_w, pw_b, pwbn_s, pwbn_b, h1);
    k_pw3 <<<dim3(160), dim3(256), 0, stream>>>(out, pw_w, pw_b, pwbn_s, pwbn_b, x);
    k_tcn <<<dim3(768), dim3(256), 0, stream>>>(h1, tc_w, tc_b, tcbn_s, tcbn_b,
                                                mpbn_s, mpbn_b, x, out);
}